// Round 15
// baseline (506.761 us; speedup 1.0000x reference)
//
#include <hip/hip_runtime.h>
#include <math.h>

typedef __attribute__((ext_vector_type(8))) short  short8;
typedef __attribute__((ext_vector_type(4))) float  f32x4;

// Problem constants: N=200000, E=100000, H=100, R=172, T=100
static constexpr int H     = 100;
static constexpr int RD    = 172;
static constexpr int WK    = 472;
static constexpr int MSTR  = 104;            // memB row stride (bf16)
static constexpr int RSTR  = 176;            // rawB row stride (bf16)
// Padded K layout: [0,104) mem[node] msg | [104,208) mem[other] | [208,384) raw
//                  [384,512) tenc | [512,640) mem[node] hh
static constexpr int NKS   = 20;
static constexpr int MB    = 32;             // nodes per tile (2 x 16-row groups)
static constexpr int GRPS  = 2;
static constexpr int BLK   = 448;            // 7 waves; wave wv owns cols wv*16..+15
static constexpr int TPB   = 4;              // tiles per block (pipelined)
static constexpr int ABUF  = GRPS * NKS * 512;     // ushorts per A buffer (20480)
static constexpr int NTT   = 28;
static constexpr int BPK_N = NTT * NKS * 64 * 8;   // 286720 bf16

// fallback (r7-style) constants
static constexpr int FB_MB = 48;
static constexpr int FB_GR = 3;

__device__ inline unsigned short f2bf(float x) {
    union { float f; unsigned u; } v; v.f = x;
    return (unsigned short)((v.u + 0x7FFFu + ((v.u >> 16) & 1u)) >> 16);
}
__device__ inline float bf2f(unsigned short b) {
    union { unsigned u; float f; } v; v.u = ((unsigned)b) << 16;
    return v.f;
}
__device__ inline unsigned pkbf(float a, float b) {
    unsigned r;
    asm("v_cvt_pk_bf16_f32 %0, %1, %2" : "=v"(r) : "v"(a), "v"(b));
    return r;
}
__device__ inline float frcp(float x) {
    float r;
    asm("v_rcp_f32 %0, %1" : "=v"(r) : "v"(x));
    return r;
}
__device__ inline f32x4 mfma16(short8 a, short8 b, f32x4 c) {
    return __builtin_amdgcn_mfma_f32_16x16x32_bf16(a, b, c, 0, 0, 0);
}
__device__ inline float4 ld4g(const float* base, int lc, int limit) {
    if (lc + 4 <= limit) return *(const float4*)(base + lc);
    return make_float4(0.f, 0.f, 0.f, 0.f);
}
__device__ inline void gl16(const unsigned short* g, unsigned short* l) {
    __builtin_amdgcn_global_load_lds(
        (const __attribute__((address_space(1))) void*)g,
        (__attribute__((address_space(3))) void*)l, 16, 0, 0);
}

// ---------------- k_pre: init + weight prep + optional bf16 conversion ----------------
__global__ __launch_bounds__(256) void k_pre(
    const float* __restrict__ mem, const float* __restrict__ raw,
    const float* __restrict__ w_ih, const float* __restrict__ w_hh,
    unsigned short* __restrict__ memB, unsigned short* __restrict__ rawB,
    unsigned short* __restrict__ B, int* __restrict__ maxt, int* __restrict__ win,
    int* __restrict__ zb, int N, int E, int docvt)
{
    int i = blockIdx.x * 256 + threadIdx.x;
    if (docvt) {
        const int nm = N * 13;
        if (i < nm) {
            int row = i / 13, o = (i - row * 13) * 8;
            float4 a = ld4g(mem + (size_t)row * 100, o, 100);
            float4 b = ld4g(mem + (size_t)row * 100, o + 4, 100);
            int4 s; s.x = (int)pkbf(a.x, a.y); s.y = (int)pkbf(a.z, a.w);
            s.z = (int)pkbf(b.x, b.y); s.w = (int)pkbf(b.z, b.w);
            *(int4*)&memB[(size_t)row * MSTR + o] = s;
            return;
        }
        i -= nm;
        const int nr = E * 22;
        if (i < nr) {
            int row = i / 22, o = (i - row * 22) * 8;
            float4 a = ld4g(raw + (size_t)row * 172, o, 172);
            float4 b = ld4g(raw + (size_t)row * 172, o + 4, 172);
            int4 s; s.x = (int)pkbf(a.x, a.y); s.y = (int)pkbf(a.z, a.w);
            s.z = (int)pkbf(b.x, b.y); s.w = (int)pkbf(b.z, b.w);
            *(int4*)&rawB[(size_t)row * RSTR + o] = s;
            return;
        }
        i -= nr;
    }
    if (i < BPK_N) {
        int idx  = i;
        int jj   = idx & 7;
        int lane = (idx >> 3) & 63;
        int rest = idx >> 9;
        int ks   = rest % NKS;
        int tile = rest / NKS;
        int kk   = ks * 32 + ((lane >> 4) << 3) + jj;
        float v = 0.f;
        if (tile < 21) {
            int gate = tile / 7;
            int tcol = (tile % 7) * 16 + (lane & 15);
            if (tcol < 100) {
                if (kk < 512) {
                    int col = -1;
                    if (kk < 100)                   col = kk;
                    else if (kk >= 104 && kk < 204) col = kk - 4;
                    else if (kk >= 208 && kk < 380) col = kk - 8;
                    else if (kk >= 384 && kk < 484) col = kk - 12;
                    if (col >= 0) v = w_ih[(gate * 100 + tcol) * WK + col];
                } else {
                    int khh = kk - 512;
                    if (gate < 2 && khh < 100)
                        v = w_hh[(gate * 100 + tcol) * H + khh];
                }
            }
        } else {
            int tcol = (tile - 21) * 16 + (lane & 15);
            int khh  = kk - 512;
            if (tcol < 100 && khh >= 0 && khh < 100)
                v = w_hh[(200 + tcol) * H + khh];
        }
        B[idx] = f2bf(v);
        return;
    }
    i -= BPK_N;
    if (i < N) { maxt[i] = (int)0x80000000; win[i] = -1; }
    if (i < 128) zb[i] = 0;
}

// ---------------- aggregation ----------------
__global__ __launch_bounds__(256) void k_maxt(const int* __restrict__ src, const int* __restrict__ dst,
                                              const int* __restrict__ t, int* __restrict__ maxt, int E) {
    int j = blockIdx.x * blockDim.x + threadIdx.x;
    if (j < E) {
        int tj = t[j];
        atomicMax(&maxt[src[j]], tj);
        atomicMax(&maxt[dst[j]], tj);
    }
}
__global__ __launch_bounds__(256) void k_win(const int* __restrict__ src, const int* __restrict__ dst,
                                             const int* __restrict__ t, const int* __restrict__ maxt,
                                             int* __restrict__ win, int E) {
    int j = blockIdx.x * blockDim.x + threadIdx.x;
    if (j < E) {
        int tj = t[j];
        int s = src[j], d = dst[j];
        if (maxt[s] == tj) atomicMax(&win[s], j);
        if (maxt[d] == tj) atomicMax(&win[d], j + E);
    }
}
__global__ __launch_bounds__(256) void k_meta(const int* __restrict__ src, const int* __restrict__ dst,
                                              const int* __restrict__ t, const int* __restrict__ last_update,
                                              const int* __restrict__ win, int4* __restrict__ meta,
                                              float* __restrict__ out_lu, int E, int N) {
    int i = blockIdx.x * blockDim.x + threadIdx.x;
    if (i >= N) return;
    int lu = last_update[i], w = win[i];
    int j = 0, other = 0, has = 0, te = lu; float dt = 0.f;
    if (w >= 0) {
        has = 1;
        int e = (w < E) ? w : (w - E);
        j = e;
        other = (w < E) ? dst[e] : src[e];
        te = t[e];
        dt = (float)(te - lu);
    }
    out_lu[i] = (float)(te > lu ? te : lu);
    int4 m; m.x = j; m.y = other; m.z = has; m.w = __float_as_int(dt);
    meta[i] = m;
}

#define LB(tile, ks) (*(const short8*)&Bpack[(((size_t)(tile) * NKS + (ks)) * 64 + lane) * 8])

// ---------------- tile staging (gl16, no data VGPRs) ----------------
__device__ inline void stage_tile(
    int node0, unsigned short* __restrict__ buf,
    const int4* __restrict__ meta, const unsigned short* __restrict__ memB,
    const unsigned short* __restrict__ rawB, const unsigned short* __restrict__ zb,
    const float* __restrict__ te_w, const float* __restrict__ te_b,
    int N, int wv, int lane, int q, int row)
{
#pragma unroll
    for (int g = 0; g < GRPS; ++g) {
        const int node_g = node0 + g * 16 + row;
        const bool val = node_g < N;
        const int4 m = val ? meta[node_g] : make_int4(0, 0, 0, 0);
        const bool has = m.z != 0;
        const float dt = __int_as_float(m.w);
        const unsigned short* pmm = has ? memB + (size_t)node_g * MSTR : zb;
        const unsigned short* pot = has ? memB + (size_t)m.y * MSTR   : zb;
        const unsigned short* prw = has ? rawB + (size_t)m.x * RSTR   : zb;
        const unsigned short* phh = val ? memB + (size_t)node_g * MSTR : zb;

        // pass 1: issue gl16 for non-tenc tiles (address math only, no data regs)
#pragma unroll
        for (int ii = 0; ii < 3; ++ii) {
            const int ks = wv + 7 * ii;
            if (ks < NKS && (ks < 12 || ks >= 16)) {
                const int k0 = ks * 32 + q * 8;
                const unsigned short* s =
                    (k0 < 104) ? pmm + k0 :
                    (k0 < 208) ? pot + (k0 - 104) :
                    (k0 < 384) ? prw + (k0 - 208) :
                                 phh + (k0 - 512);
                gl16(s, &buf[(g * NKS + ks) * 512]);
            }
        }
        // pass 2: tenc tiles (VALU + ds_write), runs while gl16s fly
#pragma unroll
        for (int ii = 0; ii < 3; ++ii) {
            const int ks = wv + 7 * ii;
            if (ks >= 12 && ks < 16) {
                const int o = (ks - 12) * 32 + q * 8;
                float4 w0 = ld4g(te_w, o, 100), w1 = ld4g(te_w, o + 4, 100);
                float4 c0 = ld4g(te_b, o, 100), c1 = ld4g(te_b, o + 4, 100);
                const float hf = has ? 1.f : 0.f;
                float v0 = hf * __cosf(fmaf(dt, w0.x, c0.x));
                float v1 = hf * __cosf(fmaf(dt, w0.y, c0.y));
                float v2 = hf * __cosf(fmaf(dt, w0.z, c0.z));
                float v3 = hf * __cosf(fmaf(dt, w0.w, c0.w));
                float v4 = hf * __cosf(fmaf(dt, w1.x, c1.x));
                float v5 = hf * __cosf(fmaf(dt, w1.y, c1.y));
                float v6 = hf * __cosf(fmaf(dt, w1.z, c1.z));
                float v7 = hf * __cosf(fmaf(dt, w1.w, c1.w));
                int4 sv;
                sv.x = (int)pkbf(v0, v1); sv.y = (int)pkbf(v2, v3);
                sv.z = (int)pkbf(v4, v5); sv.w = (int)pkbf(v6, v7);
                *(int4*)&buf[(g * NKS + ks) * 512 + lane * 8] = sv;
            }
        }
    }
}

// ---------------- fused GRU: double-buffered tile pipeline ----------------
__global__ __launch_bounds__(BLK, 4) void k_gru3(
    const unsigned short* __restrict__ memB, const unsigned short* __restrict__ rawB,
    const float* __restrict__ te_w, const float* __restrict__ te_b,
    const float* __restrict__ b_ih, const float* __restrict__ b_hh,
    const int4* __restrict__ meta, const unsigned short* __restrict__ zb,
    const unsigned short* __restrict__ Bpack,
    float* __restrict__ out_mem, int N)
{
    __shared__ unsigned short sA[2 * ABUF];   // 81920 B -> 2 blocks/CU

    const int tid  = threadIdx.x;
    const int wv   = tid >> 6;
    const int lane = tid & 63;
    const int q    = lane >> 4;
    const int row  = lane & 15;

    const int ntiles    = (N + MB - 1) / MB;
    const int tile_base = blockIdx.x * TPB;
    const int ntl       = min(TPB, ntiles - tile_base);
    if (ntl <= 0) return;

    // epilogue constants (hoisted)
    const int c   = wv * 16 + row;
    const bool cv = c < 100;
    const float br_ = cv ? b_ih[c]       + b_hh[c]       : 0.f;
    const float bz_ = cv ? b_ih[c + 100] + b_hh[c + 100] : 0.f;
    const float bin = cv ? b_ih[c + 200] : 0.f;
    const float bhn = cv ? b_hh[c + 200] : 0.f;
    const int ksh = 16 + (c >> 5);
    const int qh  = (c >> 3) & 3;
    const int e   = c & 7;

    // prologue: stage tile 0 into buf0
    stage_tile(tile_base * MB, sA, meta, memB, rawB, zb, te_w, te_b, N, wv, lane, q, row);
    __syncthreads();   // vmcnt(0)+lgkmcnt(0): buf0 ready

    for (int i = 0; i < ntl; ++i) {
        unsigned short* bufc = sA + (i & 1) * ABUF;
        unsigned short* bufn = sA + ((i + 1) & 1) * ABUF;
        const int node0 = (tile_base + i) * MB;

        // issue next tile's staging FIRST; gl16s fly under the MFMA below
        if (i + 1 < ntl)
            stage_tile(node0 + MB, bufn, meta, memB, rawB, zb, te_w, te_b, N, wv, lane, q, row);
        __builtin_amdgcn_sched_barrier(0);

        // --- MFMA on current buffer ---
        f32x4 ar[GRPS], az[GRPS], an[GRPS], ah[GRPS];
#pragma unroll
        for (int m = 0; m < GRPS; ++m) { ar[m] = (f32x4)0.f; az[m] = (f32x4)0.f; an[m] = (f32x4)0.f; ah[m] = (f32x4)0.f; }

        __builtin_amdgcn_s_setprio(1);
#pragma unroll
        for (int ks = 0; ks < NKS; ++ks) {
            short8 a0 = *(const short8*)&bufc[(0 * NKS + ks) * 512 + lane * 8];
            short8 a1 = *(const short8*)&bufc[(1 * NKS + ks) * 512 + lane * 8];
            short8 br = LB(wv, ks);
            short8 bz = LB(7 + wv, ks);
            short8 bn = (ks < 16) ? LB(14 + wv, ks) : LB(21 + wv, ks);
            ar[0] = mfma16(a0, br, ar[0]);  ar[1] = mfma16(a1, br, ar[1]);
            az[0] = mfma16(a0, bz, az[0]);  az[1] = mfma16(a1, bz, az[1]);
            if (ks < 16) { an[0] = mfma16(a0, bn, an[0]);  an[1] = mfma16(a1, bn, an[1]); }
            else         { ah[0] = mfma16(a0, bn, ah[0]);  ah[1] = mfma16(a1, bn, ah[1]); }
        }
        __builtin_amdgcn_s_setprio(0);

        // --- epilogue: gates + store; h from current buffer's hh section ---
        if (cv) {
#pragma unroll
            for (int m = 0; m < GRPS; ++m) {
#pragma unroll
                for (int r = 0; r < 4; ++r) {
                    const int node = node0 + m * 16 + q * 4 + r;
                    if (node < N) {
                        const int rw = q * 4 + r;
                        const float h  = bf2f(bufc[(m * NKS + ksh) * 512 + (qh * 16 + rw) * 8 + e]);
                        const float rg = frcp(1.f + __expf(-(ar[m][r] + br_)));
                        const float zg = frcp(1.f + __expf(-(az[m][r] + bz_)));
                        const float xn = an[m][r] + bin + rg * (ah[m][r] + bhn);
                        const float th = copysignf(1.f - 2.f * frcp(__expf(2.f * fabsf(xn)) + 1.f), xn);
                        out_mem[(size_t)node * H + c] = (1.f - zg) * th + zg * h;
                    }
                }
            }
        }

        // one barrier per tile: drains next tile's gl16 (vmcnt) + all buf reads done
        __syncthreads();
    }
}

// ---------------- fused fallback (r7-style) if ws too small ----------------
__global__ __launch_bounds__(BLK, 4) void k_gru_fused(
    const int* __restrict__ src, const int* __restrict__ dst, const int* __restrict__ t,
    const float* __restrict__ raw_msg, const float* __restrict__ memory,
    const int* __restrict__ last_update, const float* __restrict__ te_w,
    const float* __restrict__ te_b, const float* __restrict__ b_ih,
    const float* __restrict__ b_hh, const int* __restrict__ win,
    const unsigned short* __restrict__ Bpack,
    float* __restrict__ out_mem, float* __restrict__ out_lu, int E, int N)
{
    __shared__ unsigned short sA[FB_GR * NKS * 512];
    __shared__ int   s_other[FB_MB];
    __shared__ int   s_j[FB_MB];
    __shared__ int   s_has[FB_MB];
    __shared__ float s_dt[FB_MB];

    const int tid   = threadIdx.x;
    const int node0 = blockIdx.x * FB_MB;

    if (tid < FB_MB) {
        int node = node0 + tid;
        int has = 0, j = 0, other = 0; float dt = 0.f;
        if (node < N) {
            int lu = last_update[node];
            int w  = win[node];
            int te = lu;
            if (w >= 0) {
                has = 1;
                int e = (w < E) ? w : (w - E);
                j = e;
                other = (w < E) ? dst[e] : src[e];
                te = t[e];
                dt = (float)(te - lu);
            }
            out_lu[node] = (float)(te > lu ? te : lu);
        }
        s_j[tid] = j; s_other[tid] = other; s_has[tid] = has; s_dt[tid] = dt;
    }
    __syncthreads();

    if (tid < 432) {
        const int nl    = tid % 48;
        const int c0    = tid / 48;
        const int node  = node0 + nl;
        const bool valid = node < N;
        const int has   = s_has[nl];
        const float* memN = memory + (size_t)node * H;
        const float* memO = memory + (size_t)s_other[nl] * H;
        const float* rawJ = raw_msg + (size_t)s_j[nl] * RD;
        const float dt  = s_dt[nl];
        const int grp = nl >> 4;
        const int row = nl & 15;

        float4 va[8], vb[8];
#pragma unroll
        for (int it = 0; it < 8; ++it) {
            const int cc = c0 + it * 9;
            va[it] = make_float4(0.f, 0.f, 0.f, 0.f); vb[it] = va[it];
            if (cc < 67) {
                const int c = cc + 13, kb = c * 8;
                if (c < 26)      { if (has)  { va[it] = ld4g(memO, kb - 104, 100); vb[it] = ld4g(memO, kb - 100, 100); } }
                else if (c < 48) { if (has)  { va[it] = ld4g(rawJ, kb - 208, RD ); vb[it] = ld4g(rawJ, kb - 204, RD ); } }
                else if (c < 64) { }
                else             { if (valid){ va[it] = ld4g(memN, kb - 512, 100); vb[it] = ld4g(memN, kb - 508, 100); } }
            }
        }
#pragma unroll
        for (int it = 0; it < 8; ++it) {
            const int cc = c0 + it * 9;
            if (cc < 67) {
                const int c = cc + 13;
                if (c >= 48 && c < 64 && has) {
                    const int lc = c * 8 - 384;
                    float vv[8];
#pragma unroll
                    for (int x = 0; x < 8; ++x) {
                        int col = lc + x;
                        vv[x] = (col < 100) ? __cosf(fmaf(dt, te_w[col], te_b[col])) : 0.f;
                    }
                    va[it] = make_float4(vv[0], vv[1], vv[2], vv[3]);
                    vb[it] = make_float4(vv[4], vv[5], vv[6], vv[7]);
                }
                int4 sv;
                sv.x = (int)pkbf(va[it].x, va[it].y);
                sv.y = (int)pkbf(va[it].z, va[it].w);
                sv.z = (int)pkbf(vb[it].x, vb[it].y);
                sv.w = (int)pkbf(vb[it].z, vb[it].w);
                {
                    const int ks = c >> 2, sub = c & 3;
                    *(int4*)&sA[((grp * NKS + ks) * 64 + sub * 16 + row) * 8] = sv;
                }
                if (c >= 64 && c < 77) {
                    int4 sm_;
                    sm_.x = has ? sv.x : 0; sm_.y = has ? sv.y : 0;
                    sm_.z = has ? sv.z : 0; sm_.w = has ? sv.w : 0;
                    const int cm = c - 64;
                    const int ks = cm >> 2, sub = cm & 3;
                    *(int4*)&sA[((grp * NKS + ks) * 64 + sub * 16 + row) * 8] = sm_;
                }
            }
        }
    }
    __syncthreads();

    const int wv   = tid >> 6;
    const int lane = tid & 63;
    const int lrow = lane & 15;
    const int lhi  = lane >> 4;

    f32x4 ar[FB_GR], az[FB_GR], an[FB_GR], ah[FB_GR];
#pragma unroll
    for (int m = 0; m < FB_GR; ++m) { ar[m] = (f32x4)0.f; az[m] = (f32x4)0.f; an[m] = (f32x4)0.f; ah[m] = (f32x4)0.f; }

    __builtin_amdgcn_s_setprio(1);
#pragma unroll
    for (int ks = 0; ks < NKS; ++ks) {
        short8 a0 = *(const short8*)&sA[(0 * NKS + ks) * 512 + lane * 8];
        short8 a1 = *(const short8*)&sA[(1 * NKS + ks) * 512 + lane * 8];
        short8 a2 = *(const short8*)&sA[(2 * NKS + ks) * 512 + lane * 8];
        short8 br = LB(wv, ks);
        short8 bz = LB(7 + wv, ks);
        short8 bn = (ks < 16) ? LB(14 + wv, ks) : LB(21 + wv, ks);
        ar[0] = mfma16(a0, br, ar[0]);  ar[1] = mfma16(a1, br, ar[1]);  ar[2] = mfma16(a2, br, ar[2]);
        az[0] = mfma16(a0, bz, az[0]);  az[1] = mfma16(a1, bz, az[1]);  az[2] = mfma16(a2, bz, az[2]);
        if (ks < 16) { an[0] = mfma16(a0, bn, an[0]);  an[1] = mfma16(a1, bn, an[1]);  an[2] = mfma16(a2, bn, an[2]); }
        else         { ah[0] = mfma16(a0, bn, ah[0]);  ah[1] = mfma16(a1, bn, ah[1]);  ah[2] = mfma16(a2, bn, ah[2]); }
    }
    __builtin_amdgcn_s_setprio(0);

    const int c = wv * 16 + lrow;
    if (c < 100) {
        const float br_ = b_ih[c]       + b_hh[c];
        const float bz_ = b_ih[c + 100] + b_hh[c + 100];
        const float bin = b_ih[c + 200];
        const float bhn = b_hh[c + 200];
        const int ksh = 16 + (c >> 5);
        const int qh  = (c >> 3) & 3;
        const int e   = c & 7;
#pragma unroll
        for (int m = 0; m < FB_GR; ++m) {
#pragma unroll
            for (int r = 0; r < 4; ++r) {
                const int node = node0 + m * 16 + lhi * 4 + r;
                if (node < N) {
                    const int rw = lhi * 4 + r;
                    const float h  = bf2f(sA[(m * NKS + ksh) * 512 + (qh * 16 + rw) * 8 + e]);
                    const float rg = frcp(1.f + __expf(-(ar[m][r] + br_)));
                    const float zg = frcp(1.f + __expf(-(az[m][r] + bz_)));
                    const float xn = an[m][r] + bin + rg * (ah[m][r] + bhn);
                    const float th = copysignf(1.f - 2.f * frcp(__expf(2.f * fabsf(xn)) + 1.f), xn);
                    out_mem[(size_t)node * H + c] = (1.f - zg) * th + zg * h;
                }
            }
        }
    }
}

extern "C" void kernel_launch(void* const* d_in, const int* in_sizes, int n_in,
                              void* d_out, int out_size, void* d_ws, size_t ws_size,
                              hipStream_t stream)
{
    const int*   src         = (const int*)d_in[0];
    const int*   dst         = (const int*)d_in[1];
    const int*   t           = (const int*)d_in[2];
    const float* raw_msg     = (const float*)d_in[3];
    const float* memory      = (const float*)d_in[4];
    const int*   last_update = (const int*)d_in[5];
    const float* te_w        = (const float*)d_in[6];
    const float* te_b        = (const float*)d_in[7];
    const float* w_ih        = (const float*)d_in[8];
    const float* w_hh        = (const float*)d_in[9];
    const float* b_ih        = (const float*)d_in[10];
    const float* b_hh        = (const float*)d_in[11];

    const int E = in_sizes[0];   // 100000
    const int N = in_sizes[5];   // 200000

    float* out    = (float*)d_out;
    float* out_lu = out + (size_t)N * H;

    char* ws = (char*)d_ws;
    int* maxt = (int*)ws;
    int* win  = maxt + N;
    unsigned short* Bpack = (unsigned short*)(win + N);
    int4* meta = (int4*)(Bpack + BPK_N);
    unsigned short* zb   = (unsigned short*)(meta + N);
    unsigned short* memB = zb + 256;
    unsigned short* rawB = memB + (size_t)N * MSTR + 32;
    const size_t need = (size_t)((char*)(rawB + (size_t)E * RSTR) - ws) + 64;

    if (ws_size >= need) {
        const int npre = N * 13 + E * 22 + BPK_N + N;
        k_pre <<<(npre + 255) / 256, 256, 0, stream>>>(memory, raw_msg, w_ih, w_hh,
                                                       memB, rawB, Bpack, maxt, win, (int*)zb, N, E, 1);
        k_maxt<<<(E + 255) / 256, 256, 0, stream>>>(src, dst, t, maxt, E);
        k_win <<<(E + 255) / 256, 256, 0, stream>>>(src, dst, t, maxt, win, E);
        k_meta<<<(N + 255) / 256, 256, 0, stream>>>(src, dst, t, last_update, win, meta, out_lu, E, N);
        const int ntiles = (N + MB - 1) / MB;
        const int nblk   = (ntiles + TPB - 1) / TPB;
        k_gru3<<<nblk, BLK, 0, stream>>>(memB, rawB, te_w, te_b, b_ih, b_hh,
                                         meta, zb, Bpack, out, N);
    } else {
        const int npre = BPK_N + N;
        k_pre <<<(npre + 255) / 256, 256, 0, stream>>>(memory, raw_msg, w_ih, w_hh,
                                                       Bpack, Bpack, Bpack, maxt, win, (int*)zb, N, E, 0);
        k_maxt<<<(E + 255) / 256, 256, 0, stream>>>(src, dst, t, maxt, E);
        k_win <<<(E + 255) / 256, 256, 0, stream>>>(src, dst, t, maxt, win, E);
        k_gru_fused<<<(N + FB_MB - 1) / FB_MB, BLK, 0, stream>>>(src, dst, t, raw_msg, memory, last_update,
                                                                 te_w, te_b, b_ih, b_hh, win, Bpack,
                                                                 out, out_lu, E, N);
    }
}